// Round 10
// baseline (380.327 us; speedup 1.0000x reference)
//
#include <hip/hip_runtime.h>
#include <hip/hip_bf16.h>
#include <cstdint>

typedef _Float16 f16x8 __attribute__((ext_vector_type(8)));
typedef _Float16 f16x4 __attribute__((ext_vector_type(4)));
typedef float    f32x4 __attribute__((ext_vector_type(4)));

static constexpr int B = 8, S = 2048, D = 1024;
static constexpr long BSD = (long)B * S * D;   // 16,777,216
static constexpr long SD  = (long)S * D;       // 2,097,152
static constexpr long SS  = (long)S * S;       // 4,194,304
static constexpr long DD  = (long)D * D;       // 1,048,576

__device__ __forceinline__ void gload16(const void* g, void* l) {
  __builtin_amdgcn_global_load_lds(
      (const __attribute__((address_space(1))) void*)g,
      (__attribute__((address_space(3))) void*)l, 16, 0, 0);
}

// compile-time memory fence: no instruction, blocks memory-op reordering
#define CFENCE() asm volatile("" ::: "memory")

// ---------------- prep: xp = x + pos -> f16 ----------------
__global__ __launch_bounds__(256) void prep_x_kernel(
    const float* __restrict__ x, const float* __restrict__ pos,
    _Float16* __restrict__ xh) {
  long i = ((long)blockIdx.x * 256 + threadIdx.x) * 4;
  float4 xv = *(const float4*)(x + i);
  long p = i & (SD - 1);
  float4 pv = *(const float4*)(pos + p);
  f16x4 h;
  h.x = (_Float16)(xv.x + pv.x);
  h.y = (_Float16)(xv.y + pv.y);
  h.z = (_Float16)(xv.z + pv.z);
  h.w = (_Float16)(xv.w + pv.w);
  *(f16x4*)(xh + i) = h;
}

// ---------------- prep: weights -> transposed f16, LDS-tiled ----------------
__global__ __launch_bounds__(256) void prep_w_kernel(
    const float* __restrict__ Wq, const float* __restrict__ Wk,
    const float* __restrict__ Wv, const float* __restrict__ Wo,
    _Float16* __restrict__ wqkv, _Float16* __restrict__ woh) {
  __shared__ _Float16 t[64][65];
  const int c0 = blockIdx.x * 64;
  const int r0 = blockIdx.y * 64;
  const int tid = threadIdx.x;
  const int lc = tid & 63;
  const int lr4 = tid >> 6;
  const float* srcs[4] = {Wq, Wk, Wv, Wo};
  #pragma unroll
  for (int m = 0; m < 4; ++m) {
    const float* src = srcs[m];
    _Float16* dst = (m < 3) ? (wqkv + (long)m * DD) : woh;
    #pragma unroll
    for (int ii = 0; ii < 16; ++ii) {
      int row = ii * 4 + lr4;
      t[lc][row] = (_Float16)src[(long)(r0 + row) * D + c0 + lc];
    }
    __syncthreads();
    #pragma unroll
    for (int ii = 0; ii < 16; ++ii) {
      int orow = ii * 4 + lr4;
      dst[(long)(c0 + orow) * D + r0 + lc] = t[orow][lc];
    }
    __syncthreads();
  }
}

// ---------------- prep: bias concat + pw table ----------------
__global__ __launch_bounds__(256) void prep_misc_kernel(
    const float* __restrict__ bq, const float* __restrict__ bk,
    const float* __restrict__ bv,
    float* __restrict__ bcat, float* __restrict__ pwtab) {
  int i = blockIdx.x * 256 + threadIdx.x;
  if (i < 3072) {
    float v = (i < 1024) ? bq[i] : (i < 2048) ? bk[i - 1024] : bv[i - 2048];
    bcat[i] = v;
  }
  int d = i - 3072;
  if (d >= 0 && d < 2048) {
    float dist = (float)d * (1.0f / 2048.0f);
    pwtab[d] = (1.0f + 1.5f * expf(-2.0f * dist)) * (1.0f / 2.5f) * (1.0f / 32.0f);
  }
}

// ============ 256x256 8-phase MFMA GEMM: C[M,N] = A[M,K] * Bt[N,K]^T ============
// LDS: buf p (p<2) at p*65536; A halves at +0/+16384, B halves at +32768/+49152.
// st_16x32 swizzle via pre-swizzled global source + XOR'd ds_read (rule #21).
// SINGLE barrier per phase (R9, proven): {reads; stage; [c4 vm gate]; BAR; MFMA}.
// vmcnt: counted vmcnt(4) at c4; tail (s2ok false) drains vmcnt(0) [R6 fix].
// Epilogues (R10): all f16 outputs go through an LDS roundtrip so global
// stores are f16x8 / 512B-contiguous per 32 lanes (kills scalar-store
// write amplification). V keeps its transposed roundtrip (R9).

enum { EPI_QKV = 0, EPI_SF16 = 1, EPI_PVO = 2, EPI_F32B = 3 };

__device__ __forceinline__ void stage_half(
    char* smem, const _Float16* mb, int off, int k64K, int sthb,
    int dst0, int dst1) {
  gload16(mb + off, smem + sthb + dst0);
  gload16(mb + off + k64K, smem + sthb + dst1);
}

__device__ __forceinline__ void rdA(const char* p, f16x8 (&af)[4][2]) {
#pragma unroll
  for (int mr = 0; mr < 4; ++mr)
#pragma unroll
    for (int kk = 0; kk < 2; ++kk)
      af[mr][kk] = *(const f16x8*)(p + mr * 2048 + kk * 1024);
}

__device__ __forceinline__ void rdB(const char* p, f16x8 (&bf)[2][2]) {
#pragma unroll
  for (int nr = 0; nr < 2; ++nr)
#pragma unroll
    for (int kk = 0; kk < 2; ++kk)
      bf[nr][kk] = *(const f16x8*)(p + nr * 2048 + kk * 1024);
}

__device__ __forceinline__ void mfma16(const f16x8 (&af)[4][2],
                                       const f16x8 (&bf)[2][2],
                                       f32x4 (&a4)[4][2]) {
#pragma unroll
  for (int kk = 0; kk < 2; ++kk)
#pragma unroll
    for (int mr = 0; mr < 4; ++mr)
#pragma unroll
      for (int nr = 0; nr < 2; ++nr)
        a4[mr][nr] = __builtin_amdgcn_mfma_f32_16x16x32_f16(
            af[mr][kk], bf[nr][kk], a4[mr][nr], 0, 0, 0);
}

template<int EPI>
__global__ __launch_bounds__(512, 2) void gemm256_kernel(
    const _Float16* __restrict__ A, const _Float16* __restrict__ Bt,
    const float* __restrict__ bias, const float* __restrict__ pwtab,
    float* __restrict__ outF,
    _Float16* __restrict__ o0, _Float16* __restrict__ o1, _Float16* __restrict__ o2,
    int M, int N, int K, long sA, long sB, long sC)
{
  __shared__ __align__(16) char smem[131072];
  const int tid = threadIdx.x;

  // T1 XCD swizzle. z==1 grids: row-slab ownership per XCD (bijective, nwg%8==0).
  // z==8 grids (scores/PV): dispatch-id mod 8 -> batch (z pinned per XCD),
  // 4x4 super-block chunking inside the XCD for L2 working-set fit.
  int bx = blockIdx.x, by = blockIdx.y, bz = blockIdx.z;
  if (gridDim.z == 1) {
    const int bid = by * gridDim.x + bx;
    const int idx = bid >> 3;
    by = ((bid & 7) << 3) + (idx & 7);
    bx = idx >> 3;
  } else {
    const int f = (bz * gridDim.y + by) * gridDim.x + bx;   // dispatch index (x fastest)
    bz = f & 7;
    const int r = f >> 3;
    const int ri = r & 15;
    const int cid = r >> 4;
    const int cxs = gridDim.x >> 2;        // chunks along x: 2 (gx=8) or 1 (gx=4)
    bx = (cid & (cxs - 1)) * 4 + (ri & 3);
    by = (cid / cxs) * 4 + (ri >> 2);
  }
  const int z = bz;
  const int rb = by * 256;
  const int cb = bx * 256;
  const _Float16* Ag = A + (long)z * sA + (long)rb * K;
  const _Float16* Bg = Bt + (long)z * sB + (long)cb * K;

  const int lane = tid & 63;
  const int wid = tid >> 6;
  const int lrin = lane & 15;
  const int lhi = lane >> 4;
  const int rtail = (lrin * 64 + lhi * 16) ^ (((lane >> 3) & 1) << 5);
  const int aoff = ((wid >> 2) * 4) * 2048 + rtail;   // A rowgrp base
  const int boff = ((wid & 3) * 2) * 2048 + rtail;    // B rowgrp base

  // stage-side per-thread constants (int offsets; 64-bit add only at use)
  const int rin = lane >> 2;
  const int cinp = (lane & 3) ^ (((lane >> 5) & 1) << 1);  // source pre-swizzle
  const int rowc = (wid >> 1) * 16 + rin;
  const int colc = (wid & 1) * 32 + cinp * 8;
  const int stBase = rowc * K + colc;   // elem offset of this thread's chunk
  const int k64K = 64 * K;              // +64 rows
  const int h128K = 128 * K;            // +128 rows (half 1)
  const int dst0 = tid * 16;
  const int dst1 = 8192 + tid * 16;

  const int NT = K >> 6;
  f32x4 acc00[4][2] = {}, acc01[4][2] = {}, acc11[4][2] = {}, acc10[4][2] = {};

  // prologue: tile0 all 4 halves -> buf0; A0,B1 of tile1 -> buf1
  stage_half(smem, Ag, stBase,              k64K, 0,             dst0, dst1);
  stage_half(smem, Bg, stBase,              k64K, 32768,         dst0, dst1);
  stage_half(smem, Ag, stBase + h128K,      k64K, 16384,         dst0, dst1);
  stage_half(smem, Bg, stBase + h128K,      k64K, 49152,         dst0, dst1);
  stage_half(smem, Ag, stBase + 64,         k64K, 65536,         dst0, dst1);
  stage_half(smem, Bg, stBase + h128K + 64, k64K, 65536 + 49152, dst0, dst1);
  asm volatile("s_waitcnt vmcnt(4)" ::: "memory");
  __builtin_amdgcn_s_barrier();
  CFENCE();

  for (int t = 0; t < NT; ++t) {
    const int curbase = (t & 1) << 16;
    const int nxtbase = curbase ^ 65536;
    const bool s1ok = (t + 1) < NT;
    const bool s2ok = (t + 2) < NT;
    const int st1 = stBase + (t + 1) * 64;   // K-offset of tile t+1
    const int st2 = stBase + (t + 2) * 64;   // K-offset of tile t+2
    f16x8 af[4][2], bfA[2][2], bfB[2][2];

    // ---- c1: read A0,B0; stage A1(t+1)->nxt; BAR; MFMA quad(0,0)
    rdA((const char*)smem + curbase + aoff, af);
    rdB((const char*)smem + curbase + 32768 + boff, bfA);
    if (s1ok) stage_half(smem, Ag, st1 + h128K, k64K, nxtbase + 16384, dst0, dst1);
    CFENCE();
    __builtin_amdgcn_s_barrier();
    CFENCE();
    __builtin_amdgcn_s_setprio(1);
    mfma16(af, bfA, acc00);
    __builtin_amdgcn_s_setprio(0);

    // ---- c2: read B1 (A0 reused); stage B0(t+1)->nxt; BAR; MFMA quad(0,1)
    rdB((const char*)smem + curbase + 49152 + boff, bfB);
    if (s1ok) stage_half(smem, Bg, st1, k64K, nxtbase + 32768, dst0, dst1);
    CFENCE();
    __builtin_amdgcn_s_barrier();
    CFENCE();
    __builtin_amdgcn_s_setprio(1);
    mfma16(af, bfB, acc01);
    __builtin_amdgcn_s_setprio(0);

    // ---- c3: read A1 (B1 reused); stage A0(t+2)->cur; BAR; MFMA quad(1,1)
    rdA((const char*)smem + curbase + 16384 + aoff, af);
    if (s2ok) stage_half(smem, Ag, st2, k64K, curbase + 0, dst0, dst1);
    CFENCE();
    __builtin_amdgcn_s_barrier();
    CFENCE();
    __builtin_amdgcn_s_setprio(1);
    mfma16(af, bfB, acc11);
    __builtin_amdgcn_s_setprio(0);

    // ---- c4: re-read B0 (A1 reused); stage B1(t+2)->cur; vm gate; BAR; MFMA quad(1,0)
    rdB((const char*)smem + curbase + 32768 + boff, bfA);
    if (s2ok) stage_half(smem, Bg, st2 + h128K, k64K, curbase + 49152, dst0, dst1);
    if (s2ok) {
      asm volatile("s_waitcnt vmcnt(4)" ::: "memory");
    } else {
      asm volatile("s_waitcnt vmcnt(0)" ::: "memory");  // tail drain (R6 fix)
    }
    CFENCE();
    __builtin_amdgcn_s_barrier();
    CFENCE();
    __builtin_amdgcn_s_setprio(1);
    mfma16(af, bfA, acc10);
    __builtin_amdgcn_s_setprio(0);
  }

  // epilogue: C/D layout col = lane&15, row = (lane>>4)*4 + r  [m89-verified]
  const int wrow = (wid >> 2) * 64;
  const int wcol = (wid & 3) * 32;
  const int matid = (EPI == EPI_QKV) ? (cb >> 10) : 0;

  if (EPI == EPI_F32B) {
    // f32 direct stores: 16 lanes x 4B = full 64B lines, no amplification
    auto epi = [&](const f32x4 (&a4)[4][2], int qm, int qn) {
#pragma unroll
      for (int nr = 0; nr < 2; ++nr) {
        const int col = cb + qn * 128 + wcol + nr * 16 + lrin;
        const float bv = bias[col];
#pragma unroll
        for (int mr = 0; mr < 4; ++mr) {
          const int rowb = rb + qm * 128 + wrow + mr * 16 + lhi * 4;
          const f32x4 v4 = a4[mr][nr];
#pragma unroll
          for (int r = 0; r < 4; ++r)
            outF[(long)(rowb + r) * N + col] = v4[r] + bv;
        }
      }
    };
    epi(acc00, 0, 0);
    epi(acc01, 0, 1);
    epi(acc11, 1, 1);
    epi(acc10, 1, 0);
  } else if (EPI == EPI_QKV && matid == 2) {
    // ---- V: LDS-transpose epilogue (coalesced [d][t] stores), R9-proven ----
    __syncthreads();   // all waves' K-loop LDS reads complete
    auto vfrag = [&](const f32x4 (&a4)[4][2], int qm, int qn) {
#pragma unroll
      for (int nr = 0; nr < 2; ++nr) {
        const int dl = qn * 128 + wcol + nr * 16 + lrin;   // 0..255
        const float bv = bias[cb + dl];
        const int xr = (dl & 7) << 4;
#pragma unroll
        for (int mr = 0; mr < 4; ++mr) {
          const int tl = qm * 128 + wrow + mr * 16 + lhi * 4;  // 0..252 step 4
          const f32x4 v4 = a4[mr][nr];
          f16x4 p;
          p[0] = (_Float16)(v4[0] + bv);
          p[1] = (_Float16)(v4[1] + bv);
          p[2] = (_Float16)(v4[2] + bv);
          p[3] = (_Float16)(v4[3] + bv);
          *(f16x4*)(smem + dl * 512 + ((tl * 2) ^ xr)) = p;
        }
      }
    };
    vfrag(acc00, 0, 0);
    vfrag(acc01, 0, 1);
    vfrag(acc11, 1, 1);
    vfrag(acc10, 1, 0);
    __syncthreads();
    const int t0 = rb & (S - 1);
    const int bbk = rb >> 11;
    const int lr5 = tid & 31;       // 32 threads per d-row
    const int dr0 = tid >> 5;       // 0..15
#pragma unroll
    for (int pass = 0; pass < 16; ++pass) {
      const int dl = pass * 16 + dr0;
      const f16x8 vv = *(const f16x8*)(smem + dl * 512 + ((lr5 * 16) ^ ((dl & 7) << 4)));
      *(f16x8*)(o2 + (long)bbk * SD + (long)(cb - 2048 + dl) * S + t0 + lr5 * 8) = vv;
    }
  } else {
    // ---- row-major LDS roundtrip (Q, K, scores, PV): coalesced f16x8 stores ----
    // LDS [256 rows][256 cols] f16 = 128 KB; 16B slot-XOR: slot = (cl>>3)^(row&31).
    __syncthreads();   // all waves' K-loop LDS reads complete
    auto toLds = [&](const f32x4 (&a4)[4][2], int qm, int qn) {
#pragma unroll
      for (int nr = 0; nr < 2; ++nr) {
        const int cl = qn * 128 + wcol + nr * 16 + lrin;       // local col 0..255
        const float bv = (EPI == EPI_QKV) ? bias[cb + cl] : 0.0f;
#pragma unroll
        for (int mr = 0; mr < 4; ++mr) {
          const int tl0 = qm * 128 + wrow + mr * 16 + lhi * 4;
          const f32x4 v4 = a4[mr][nr];
#pragma unroll
          for (int r = 0; r < 4; ++r) {
            const int tl = tl0 + r;
            float v = v4[r];
            if (EPI == EPI_QKV) {
              v += bv;
            } else if (EPI == EPI_SF16) {
              int dd = (rb + tl) - (cb + cl); if (dd < 0) dd = -dd;
              v *= pwtab[dd];
            }
            *(_Float16*)(smem + tl * 512 + ((((cl >> 3) ^ (tl & 31))) << 4) + (cl & 7) * 2) =
                (_Float16)v;
          }
        }
      }
    };
    toLds(acc00, 0, 0);
    toLds(acc01, 0, 1);
    toLds(acc11, 1, 1);
    toLds(acc10, 1, 0);
    __syncthreads();
    const int lr5 = tid & 31;       // col chunk (x8)
    const int r0 = tid >> 5;        // row 0..15
#pragma unroll
    for (int pass = 0; pass < 16; ++pass) {
      const int row = pass * 16 + r0;
      const f16x8 vv = *(const f16x8*)(smem + row * 512 + ((lr5 ^ (row & 31)) << 4));
      if (EPI == EPI_QKV) {
        _Float16* dst = matid ? o1 : o0;
        *(f16x8*)(dst + (long)(rb + row) * 1024 + (cb & 1023) + lr5 * 8) = vv;
      } else {
        *(f16x8*)(o0 + (long)z * sC + (long)(rb + row) * N + cb + lr5 * 8) = vv;
      }
    }
  }
}

// ---------------- row softmax over 2048: f16 in -> f32 attn + f16 copy ----------------
__global__ __launch_bounds__(256) void softmax_kernel(
    const _Float16* __restrict__ sbf, float* __restrict__ attn,
    _Float16* __restrict__ abf) {
  const long base = (long)blockIdx.x * S + threadIdx.x * 8;
  const int tid = threadIdx.x;
  const f16x8 sv = *(const f16x8*)(sbf + base);
  float v[8];
  #pragma unroll
  for (int t = 0; t < 8; ++t) v[t] = (float)sv[t];
  float m = fmaxf(fmaxf(fmaxf(v[0], v[1]), fmaxf(v[2], v[3])),
                  fmaxf(fmaxf(v[4], v[5]), fmaxf(v[6], v[7])));
  #pragma unroll
  for (int sh = 1; sh < 64; sh <<= 1) m = fmaxf(m, __shfl_xor(m, sh));
  __shared__ float red[8];
  const int w = tid >> 6;
  if ((tid & 63) == 0) red[w] = m;
  __syncthreads();
  m = fmaxf(fmaxf(red[0], red[1]), fmaxf(red[2], red[3]));
  float e[8];
  #pragma unroll
  for (int t = 0; t < 8; ++t) e[t] = expf(v[t] - m);
  float s8 = ((e[0] + e[1]) + (e[2] + e[3])) + ((e[4] + e[5]) + (e[6] + e[7]));
  #pragma unroll
  for (int sh = 1; sh < 64; sh <<= 1) s8 += __shfl_xor(s8, sh);
  if ((tid & 63) == 0) red[4 + w] = s8;
  __syncthreads();
  const float inv = 1.0f / ((red[4] + red[5]) + (red[6] + red[7]));
  float4 o0 = make_float4(e[0] * inv, e[1] * inv, e[2] * inv, e[3] * inv);
  float4 o1 = make_float4(e[4] * inv, e[5] * inv, e[6] * inv, e[7] * inv);
  *(float4*)(attn + base) = o0;
  *(float4*)(attn + base + 4) = o1;
  f16x8 hb;
  hb[0] = (_Float16)o0.x; hb[1] = (_Float16)o0.y;
  hb[2] = (_Float16)o0.z; hb[3] = (_Float16)o0.w;
  hb[4] = (_Float16)o1.x; hb[5] = (_Float16)o1.y;
  hb[6] = (_Float16)o1.z; hb[7] = (_Float16)o1.w;
  *(f16x8*)(abf + base) = hb;
}

extern "C" void kernel_launch(void* const* d_in, const int* in_sizes, int n_in,
                              void* d_out, int out_size, void* d_ws, size_t ws_size,
                              hipStream_t stream) {
  const float* x   = (const float*)d_in[0];
  const float* pos = (const float*)d_in[1];
  const float* Wq  = (const float*)d_in[2];
  const float* bq  = (const float*)d_in[3];
  const float* Wk  = (const float*)d_in[4];
  const float* bk  = (const float*)d_in[5];
  const float* Wv  = (const float*)d_in[6];
  const float* bv  = (const float*)d_in[7];
  const float* Wo  = (const float*)d_in[8];
  const float* bo  = (const float*)d_in[9];

  float* outp  = (float*)d_out;          // [B,S,D] f32
  float* attnp = outp + BSD;             // [B,S,S] f32 (final attn)

  // workspace layout (~243 MB of ws)
  _Float16* wqkv = (_Float16*)d_ws;              // [3072][1024] f16
  _Float16* woh  = wqkv + 3 * DD;                // [1024][1024] f16
  float*    bcat = (float*)(woh + DD);           // [3072] f32
  float*    pwtab = bcat + 3072;                 // [2048] f32
  _Float16* qh  = (_Float16*)(pwtab + 2048);     // [B*S][D] f16
  _Float16* kh  = qh + BSD;                      // [B*S][D]
  _Float16* vt  = kh + BSD;                      // [B][D][S]
  _Float16* sbf = vt + BSD;                      // [B][S][S] f16 scores
  _Float16* abf = sbf + (long)B * SS;            // [B][S][S] f16 attn
  _Float16* hbf = qh;                            // PV out reuses qh

  _Float16* xph = (_Float16*)attnp;              // xp f16 in attn region of d_out

  dim3 blk(256);
  prep_w_kernel<<<dim3(16, 16), blk, 0, stream>>>(Wq, Wk, Wv, Wo, wqkv, woh);
  prep_misc_kernel<<<dim3(20), blk, 0, stream>>>(bq, bk, bv, bcat, pwtab);
  prep_x_kernel<<<dim3((int)(BSD / 1024)), blk, 0, stream>>>(x, pos, xph);

  dim3 blk5(512);
  // fused QKV projection: [16384,1024] @ [3072,1024]^T
  gemm256_kernel<EPI_QKV><<<dim3(12, 64, 1), blk5, 0, stream>>>(
      xph, wqkv, bcat, nullptr, nullptr, qh, kh, vt, B * S, 3 * D, D, 0, 0, 0);

  // scores (f16, pw-scaled): per-batch [2048,1024] @ [2048,1024]^T
  gemm256_kernel<EPI_SF16><<<dim3(8, 8, B), blk5, 0, stream>>>(
      qh, kh, nullptr, pwtab, nullptr, sbf, nullptr, nullptr, S, S, D, SD, SD, SS);

  softmax_kernel<<<dim3(B * S), blk, 0, stream>>>(sbf, attnp, abf);

  // PV: per-batch [2048,2048] @ [1024,2048]^T
  gemm256_kernel<EPI_PVO><<<dim3(4, 8, B), blk5, 0, stream>>>(
      abf, vt, nullptr, nullptr, nullptr, hbf, nullptr, nullptr, S, D, S, SS, SD, SD);

  // out-proj: [16384,1024] @ [1024,1024]^T + bo -> f32
  gemm256_kernel<EPI_F32B><<<dim3(4, 64, 1), blk5, 0, stream>>>(
      hbf, woh, bo, nullptr, outp, nullptr, nullptr, nullptr, B * S, D, D, 0, 0, 0);
}

// Round 11
// 374.623 us; speedup vs baseline: 1.0152x; 1.0152x over previous
//
#include <hip/hip_runtime.h>
#include <hip/hip_bf16.h>
#include <cstdint>

typedef _Float16 f16x8 __attribute__((ext_vector_type(8)));
typedef _Float16 f16x4 __attribute__((ext_vector_type(4)));
typedef float    f32x4 __attribute__((ext_vector_type(4)));

static constexpr int B = 8, S = 2048, D = 1024;
static constexpr long BSD = (long)B * S * D;   // 16,777,216
static constexpr long SD  = (long)S * D;       // 2,097,152
static constexpr long SS  = (long)S * S;       // 4,194,304
static constexpr long DD  = (long)D * D;       // 1,048,576

__device__ __forceinline__ void gload16(const void* g, void* l) {
  __builtin_amdgcn_global_load_lds(
      (const __attribute__((address_space(1))) void*)g,
      (__attribute__((address_space(3))) void*)l, 16, 0, 0);
}

// compile-time memory fence: no instruction, blocks memory-op reordering
#define CFENCE() asm volatile("" ::: "memory")

// ---------------- prep: xp = x + pos -> f16 ----------------
__global__ __launch_bounds__(256) void prep_x_kernel(
    const float* __restrict__ x, const float* __restrict__ pos,
    _Float16* __restrict__ xh) {
  long i = ((long)blockIdx.x * 256 + threadIdx.x) * 4;
  float4 xv = *(const float4*)(x + i);
  long p = i & (SD - 1);
  float4 pv = *(const float4*)(pos + p);
  f16x4 h;
  h.x = (_Float16)(xv.x + pv.x);
  h.y = (_Float16)(xv.y + pv.y);
  h.z = (_Float16)(xv.z + pv.z);
  h.w = (_Float16)(xv.w + pv.w);
  *(f16x4*)(xh + i) = h;
}

// ---------------- prep: weights -> transposed f16, LDS-tiled ----------------
__global__ __launch_bounds__(256) void prep_w_kernel(
    const float* __restrict__ Wq, const float* __restrict__ Wk,
    const float* __restrict__ Wv, const float* __restrict__ Wo,
    _Float16* __restrict__ wqkv, _Float16* __restrict__ woh) {
  __shared__ _Float16 t[64][65];
  const int c0 = blockIdx.x * 64;
  const int r0 = blockIdx.y * 64;
  const int tid = threadIdx.x;
  const int lc = tid & 63;
  const int lr4 = tid >> 6;
  const float* srcs[4] = {Wq, Wk, Wv, Wo};
  #pragma unroll
  for (int m = 0; m < 4; ++m) {
    const float* src = srcs[m];
    _Float16* dst = (m < 3) ? (wqkv + (long)m * DD) : woh;
    #pragma unroll
    for (int ii = 0; ii < 16; ++ii) {
      int row = ii * 4 + lr4;
      t[lc][row] = (_Float16)src[(long)(r0 + row) * D + c0 + lc];
    }
    __syncthreads();
    #pragma unroll
    for (int ii = 0; ii < 16; ++ii) {
      int orow = ii * 4 + lr4;
      dst[(long)(c0 + orow) * D + r0 + lc] = t[orow][lc];
    }
    __syncthreads();
  }
}

// ---------------- prep: bias concat + pw table ----------------
__global__ __launch_bounds__(256) void prep_misc_kernel(
    const float* __restrict__ bq, const float* __restrict__ bk,
    const float* __restrict__ bv,
    float* __restrict__ bcat, float* __restrict__ pwtab) {
  int i = blockIdx.x * 256 + threadIdx.x;
  if (i < 3072) {
    float v = (i < 1024) ? bq[i] : (i < 2048) ? bk[i - 1024] : bv[i - 2048];
    bcat[i] = v;
  }
  int d = i - 3072;
  if (d >= 0 && d < 2048) {
    float dist = (float)d * (1.0f / 2048.0f);
    pwtab[d] = (1.0f + 1.5f * expf(-2.0f * dist)) * (1.0f / 2.5f) * (1.0f / 32.0f);
  }
}

// ============ 256x256 MFMA GEMM, 2 phases per K-tile: C = A * Bt^T ============
// LDS: buf p (p<2) at p*65536; A halves at +0/+16384, B halves at +32768/+49152.
// st_16x32 swizzle via pre-swizzled global source + XOR'd ds_read (rule #21).
// Per tile: p1 {lgkm0; stage A1,B0(t+1)->nxt; rd A0,B0,B1; bar; MFMA q00,q01}
//           p2 {lgkm0; stage A0,B1(t+2)->cur; rd A1; vm gate; bar; MFMA q11,q10}
// Gate: vmcnt(4) retires everything except this p2's own 4 loads -> all of
// tile t+1's halves retired before its p1 reads. Tail: s2ok false -> vmcnt(0)
// (drains p1's stages AND leaves LDS quiet for the smem-reusing epilogue).
// Phase-leading lgkmcnt(0) is ~free and rigorously orders slot-overwriting
// stages after the previous readers' ds_read completion (R11 ledger).

enum { EPI_QKV = 0, EPI_SF16 = 1, EPI_PVO = 2, EPI_F32B = 3 };

__device__ __forceinline__ void stage_half(
    char* smem, const _Float16* mb, int off, int k64K, int sthb,
    int dst0, int dst1) {
  gload16(mb + off, smem + sthb + dst0);
  gload16(mb + off + k64K, smem + sthb + dst1);
}

__device__ __forceinline__ void rdA(const char* p, f16x8 (&af)[4][2]) {
#pragma unroll
  for (int mr = 0; mr < 4; ++mr)
#pragma unroll
    for (int kk = 0; kk < 2; ++kk)
      af[mr][kk] = *(const f16x8*)(p + mr * 2048 + kk * 1024);
}

__device__ __forceinline__ void rdB(const char* p, f16x8 (&bf)[2][2]) {
#pragma unroll
  for (int nr = 0; nr < 2; ++nr)
#pragma unroll
    for (int kk = 0; kk < 2; ++kk)
      bf[nr][kk] = *(const f16x8*)(p + nr * 2048 + kk * 1024);
}

__device__ __forceinline__ void mfma16(const f16x8 (&af)[4][2],
                                       const f16x8 (&bf)[2][2],
                                       f32x4 (&a4)[4][2]) {
#pragma unroll
  for (int kk = 0; kk < 2; ++kk)
#pragma unroll
    for (int mr = 0; mr < 4; ++mr)
#pragma unroll
      for (int nr = 0; nr < 2; ++nr)
        a4[mr][nr] = __builtin_amdgcn_mfma_f32_16x16x32_f16(
            af[mr][kk], bf[nr][kk], a4[mr][nr], 0, 0, 0);
}

template<int EPI>
__global__ __launch_bounds__(512, 2) void gemm256_kernel(
    const _Float16* __restrict__ A, const _Float16* __restrict__ Bt,
    const float* __restrict__ bias, const float* __restrict__ pwtab,
    float* __restrict__ outF,
    _Float16* __restrict__ o0, _Float16* __restrict__ o1, _Float16* __restrict__ o2,
    int M, int N, int K, long sA, long sB, long sC)
{
  __shared__ __align__(16) char smem[131072];
  const int tid = threadIdx.x;

  // T1 XCD swizzle. z==1 grids: row-slab ownership per XCD (bijective, nwg%8==0).
  // z==8 grids: dispatch-id mod 8 -> batch (z pinned per XCD), 4x4 chunking.
  int bx = blockIdx.x, by = blockIdx.y, bz = blockIdx.z;
  if (gridDim.z == 1) {
    const int bid = by * gridDim.x + bx;
    const int idx = bid >> 3;
    by = ((bid & 7) << 3) + (idx & 7);
    bx = idx >> 3;
  } else {
    const int f = (bz * gridDim.y + by) * gridDim.x + bx;   // dispatch index (x fastest)
    bz = f & 7;
    const int r = f >> 3;
    const int ri = r & 15;
    const int cid = r >> 4;
    const int cxs = gridDim.x >> 2;        // chunks along x: 2 (gx=8) or 1 (gx=4)
    bx = (cid & (cxs - 1)) * 4 + (ri & 3);
    by = (cid / cxs) * 4 + (ri >> 2);
  }
  const int z = bz;
  const int rb = by * 256;
  const int cb = bx * 256;
  const _Float16* Ag = A + (long)z * sA + (long)rb * K;
  const _Float16* Bg = Bt + (long)z * sB + (long)cb * K;

  const int lane = tid & 63;
  const int wid = tid >> 6;
  const int lrin = lane & 15;
  const int lhi = lane >> 4;
  const int rtail = (lrin * 64 + lhi * 16) ^ (((lane >> 3) & 1) << 5);
  const int aoff = ((wid >> 2) * 4) * 2048 + rtail;   // A rowgrp base
  const int boff = ((wid & 3) * 2) * 2048 + rtail;    // B rowgrp base

  // stage-side per-thread constants (int offsets; 64-bit add only at use)
  const int rin = lane >> 2;
  const int cinp = (lane & 3) ^ (((lane >> 5) & 1) << 1);  // source pre-swizzle
  const int rowc = (wid >> 1) * 16 + rin;
  const int colc = (wid & 1) * 32 + cinp * 8;
  const int stBase = rowc * K + colc;   // elem offset of this thread's chunk
  const int k64K = 64 * K;              // +64 rows
  const int h128K = 128 * K;            // +128 rows (half 1)
  const int dst0 = tid * 16;
  const int dst1 = 8192 + tid * 16;

  const int NT = K >> 6;
  f32x4 acc00[4][2] = {}, acc01[4][2] = {}, acc11[4][2] = {}, acc10[4][2] = {};

  // prologue: tile0 all 4 halves -> buf0; A0,B1 of tile1 -> buf1
  stage_half(smem, Ag, stBase,              k64K, 0,             dst0, dst1);
  stage_half(smem, Bg, stBase,              k64K, 32768,         dst0, dst1);
  stage_half(smem, Ag, stBase + h128K,      k64K, 16384,         dst0, dst1);
  stage_half(smem, Bg, stBase + h128K,      k64K, 49152,         dst0, dst1);
  stage_half(smem, Ag, stBase + 64,         k64K, 65536,         dst0, dst1);
  stage_half(smem, Bg, stBase + h128K + 64, k64K, 65536 + 49152, dst0, dst1);
  asm volatile("s_waitcnt vmcnt(4)" ::: "memory");
  __builtin_amdgcn_s_barrier();
  CFENCE();

  for (int t = 0; t < NT; ++t) {
    const int curbase = (t & 1) << 16;
    const int nxtbase = curbase ^ 65536;
    const bool s1ok = (t + 1) < NT;
    const bool s2ok = (t + 2) < NT;
    const int st1 = stBase + (t + 1) * 64;   // K-offset of tile t+1
    const int st2 = stBase + (t + 2) * 64;   // K-offset of tile t+2
    f16x8 af[4][2], bf0[2][2], bf1[2][2];

    // ---- p1: stage A1,B0(t+1)->nxt; rd A0,B0,B1; BAR; MFMA q00,q01
    asm volatile("s_waitcnt lgkmcnt(0)" ::: "memory");
    if (s1ok) {
      stage_half(smem, Ag, st1 + h128K, k64K, nxtbase + 16384, dst0, dst1);
      stage_half(smem, Bg, st1,         k64K, nxtbase + 32768, dst0, dst1);
    }
    rdA((const char*)smem + curbase + aoff, af);
    rdB((const char*)smem + curbase + 32768 + boff, bf0);
    rdB((const char*)smem + curbase + 49152 + boff, bf1);
    CFENCE();
    __builtin_amdgcn_s_barrier();
    CFENCE();
    __builtin_amdgcn_s_setprio(1);
    mfma16(af, bf0, acc00);
    mfma16(af, bf1, acc01);
    __builtin_amdgcn_s_setprio(0);

    // ---- p2: stage A0,B1(t+2)->cur; rd A1; vm gate; BAR; MFMA q11,q10
    asm volatile("s_waitcnt lgkmcnt(0)" ::: "memory");
    if (s2ok) {
      stage_half(smem, Ag, st2,         k64K, curbase + 0,     dst0, dst1);
      stage_half(smem, Bg, st2 + h128K, k64K, curbase + 49152, dst0, dst1);
    }
    rdA((const char*)smem + curbase + 16384 + aoff, af);
    if (s2ok) {
      asm volatile("s_waitcnt vmcnt(4)" ::: "memory");
    } else {
      asm volatile("s_waitcnt vmcnt(0)" ::: "memory");  // tail drain (R6 fix)
    }
    CFENCE();
    __builtin_amdgcn_s_barrier();
    CFENCE();
    __builtin_amdgcn_s_setprio(1);
    mfma16(af, bf1, acc11);
    mfma16(af, bf0, acc10);
    __builtin_amdgcn_s_setprio(0);
  }

  // epilogue: C/D layout col = lane&15, row = (lane>>4)*4 + r  [m89-verified]
  const int wrow = (wid >> 2) * 64;
  const int wcol = (wid & 3) * 32;
  const int matid = (EPI == EPI_QKV) ? (cb >> 10) : 0;

  if (EPI == EPI_F32B) {
    // f32 direct stores: 16 lanes x 4B = full 64B lines, no amplification
    auto epi = [&](const f32x4 (&a4)[4][2], int qm, int qn) {
#pragma unroll
      for (int nr = 0; nr < 2; ++nr) {
        const int col = cb + qn * 128 + wcol + nr * 16 + lrin;
        const float bv = bias[col];
#pragma unroll
        for (int mr = 0; mr < 4; ++mr) {
          const int rowb = rb + qm * 128 + wrow + mr * 16 + lhi * 4;
          const f32x4 v4 = a4[mr][nr];
#pragma unroll
          for (int r = 0; r < 4; ++r)
            outF[(long)(rowb + r) * N + col] = v4[r] + bv;
        }
      }
    };
    epi(acc00, 0, 0);
    epi(acc01, 0, 1);
    epi(acc11, 1, 1);
    epi(acc10, 1, 0);
  } else if (EPI == EPI_QKV && matid == 2) {
    // ---- V: LDS-transpose epilogue (coalesced [d][t] stores), R9-proven ----
    __syncthreads();   // all waves' K-loop LDS reads complete
    auto vfrag = [&](const f32x4 (&a4)[4][2], int qm, int qn) {
#pragma unroll
      for (int nr = 0; nr < 2; ++nr) {
        const int dl = qn * 128 + wcol + nr * 16 + lrin;   // 0..255
        const float bv = bias[cb + dl];
        const int xr = (dl & 7) << 4;
#pragma unroll
        for (int mr = 0; mr < 4; ++mr) {
          const int tl = qm * 128 + wrow + mr * 16 + lhi * 4;  // 0..252 step 4
          const f32x4 v4 = a4[mr][nr];
          f16x4 p;
          p[0] = (_Float16)(v4[0] + bv);
          p[1] = (_Float16)(v4[1] + bv);
          p[2] = (_Float16)(v4[2] + bv);
          p[3] = (_Float16)(v4[3] + bv);
          *(f16x4*)(smem + dl * 512 + ((tl * 2) ^ xr)) = p;
        }
      }
    };
    vfrag(acc00, 0, 0);
    vfrag(acc01, 0, 1);
    vfrag(acc11, 1, 1);
    vfrag(acc10, 1, 0);
    __syncthreads();
    const int t0 = rb & (S - 1);
    const int bbk = rb >> 11;
    const int lr5 = tid & 31;       // 32 threads per d-row
    const int dr0 = tid >> 5;       // 0..15
#pragma unroll
    for (int pass = 0; pass < 16; ++pass) {
      const int dl = pass * 16 + dr0;
      const f16x8 vv = *(const f16x8*)(smem + dl * 512 + ((lr5 * 16) ^ ((dl & 7) << 4)));
      *(f16x8*)(o2 + (long)bbk * SD + (long)(cb - 2048 + dl) * S + t0 + lr5 * 8) = vv;
    }
  } else {
    // ---- row-major LDS roundtrip (Q, K, scores, PV): coalesced f16x8 stores ----
    // LDS [256 rows][256 cols] f16 = 128 KB; 16B slot-XOR: slot = (cl>>3)^(row&31).
    __syncthreads();   // all waves' K-loop LDS reads complete
    auto toLds = [&](const f32x4 (&a4)[4][2], int qm, int qn) {
#pragma unroll
      for (int nr = 0; nr < 2; ++nr) {
        const int cl = qn * 128 + wcol + nr * 16 + lrin;       // local col 0..255
        const float bv = (EPI == EPI_QKV) ? bias[cb + cl] : 0.0f;
#pragma unroll
        for (int mr = 0; mr < 4; ++mr) {
          const int tl0 = qm * 128 + wrow + mr * 16 + lhi * 4;
          const f32x4 v4 = a4[mr][nr];
#pragma unroll
          for (int r = 0; r < 4; ++r) {
            const int tl = tl0 + r;
            float v = v4[r];
            if (EPI == EPI_QKV) {
              v += bv;
            } else if (EPI == EPI_SF16) {
              int dd = (rb + tl) - (cb + cl); if (dd < 0) dd = -dd;
              v *= pwtab[dd];
            }
            *(_Float16*)(smem + tl * 512 + ((((cl >> 3) ^ (tl & 31))) << 4) + (cl & 7) * 2) =
                (_Float16)v;
          }
        }
      }
    };
    toLds(acc00, 0, 0);
    toLds(acc01, 0, 1);
    toLds(acc11, 1, 1);
    toLds(acc10, 1, 0);
    __syncthreads();
    const int lr5 = tid & 31;       // col chunk (x8)
    const int r0 = tid >> 5;        // row 0..15
#pragma unroll
    for (int pass = 0; pass < 16; ++pass) {
      const int row = pass * 16 + r0;
      const f16x8 vv = *(const f16x8*)(smem + row * 512 + ((lr5 ^ (row & 31)) << 4));
      if (EPI == EPI_QKV) {
        _Float16* dst = matid ? o1 : o0;
        *(f16x8*)(dst + (long)(rb + row) * 1024 + (cb & 1023) + lr5 * 8) = vv;
      } else {
        *(f16x8*)(o0 + (long)z * sC + (long)(rb + row) * N + cb + lr5 * 8) = vv;
      }
    }
  }
}

// ---------------- row softmax over 2048: f16 in -> f32 attn + f16 copy ----------------
__global__ __launch_bounds__(256) void softmax_kernel(
    const _Float16* __restrict__ sbf, float* __restrict__ attn,
    _Float16* __restrict__ abf) {
  const long base = (long)blockIdx.x * S + threadIdx.x * 8;
  const int tid = threadIdx.x;
  const f16x8 sv = *(const f16x8*)(sbf + base);
  float v[8];
  #pragma unroll
  for (int t = 0; t < 8; ++t) v[t] = (float)sv[t];
  float m = fmaxf(fmaxf(fmaxf(v[0], v[1]), fmaxf(v[2], v[3])),
                  fmaxf(fmaxf(v[4], v[5]), fmaxf(v[6], v[7])));
  #pragma unroll
  for (int sh = 1; sh < 64; sh <<= 1) m = fmaxf(m, __shfl_xor(m, sh));
  __shared__ float red[8];
  const int w = tid >> 6;
  if ((tid & 63) == 0) red[w] = m;
  __syncthreads();
  m = fmaxf(fmaxf(red[0], red[1]), fmaxf(red[2], red[3]));
  float e[8];
  #pragma unroll
  for (int t = 0; t < 8; ++t) e[t] = expf(v[t] - m);
  float s8 = ((e[0] + e[1]) + (e[2] + e[3])) + ((e[4] + e[5]) + (e[6] + e[7]));
  #pragma unroll
  for (int sh = 1; sh < 64; sh <<= 1) s8 += __shfl_xor(s8, sh);
  if ((tid & 63) == 0) red[4 + w] = s8;
  __syncthreads();
  const float inv = 1.0f / ((red[4] + red[5]) + (red[6] + red[7]));
  float4 o0 = make_float4(e[0] * inv, e[1] * inv, e[2] * inv, e[3] * inv);
  float4 o1 = make_float4(e[4] * inv, e[5] * inv, e[6] * inv, e[7] * inv);
  *(float4*)(attn + base) = o0;
  *(float4*)(attn + base + 4) = o1;
  f16x8 hb;
  hb[0] = (_Float16)o0.x; hb[1] = (_Float16)o0.y;
  hb[2] = (_Float16)o0.z; hb[3] = (_Float16)o0.w;
  hb[4] = (_Float16)o1.x; hb[5] = (_Float16)o1.y;
  hb[6] = (_Float16)o1.z; hb[7] = (_Float16)o1.w;
  *(f16x8*)(abf + base) = hb;
}

extern "C" void kernel_launch(void* const* d_in, const int* in_sizes, int n_in,
                              void* d_out, int out_size, void* d_ws, size_t ws_size,
                              hipStream_t stream) {
  const float* x   = (const float*)d_in[0];
  const float* pos = (const float*)d_in[1];
  const float* Wq  = (const float*)d_in[2];
  const float* bq  = (const float*)d_in[3];
  const float* Wk  = (const float*)d_in[4];
  const float* bk  = (const float*)d_in[5];
  const float* Wv  = (const float*)d_in[6];
  const float* bv  = (const float*)d_in[7];
  const float* Wo  = (const float*)d_in[8];
  const float* bo  = (const float*)d_in[9];

  float* outp  = (float*)d_out;          // [B,S,D] f32
  float* attnp = outp + BSD;             // [B,S,S] f32 (final attn)

  // workspace layout (~243 MB of ws)
  _Float16* wqkv = (_Float16*)d_ws;              // [3072][1024] f16
  _Float16* woh  = wqkv + 3 * DD;                // [1024][1024] f16
  float*    bcat = (float*)(woh + DD);           // [3072] f32
  float*    pwtab = bcat + 3072;                 // [2048] f32
  _Float16* qh  = (_Float16*)(pwtab + 2048);     // [B*S][D] f16
  _Float16* kh  = qh + BSD;                      // [B*S][D]
  _Float16* vt  = kh + BSD;                      // [B][D][S]
  _Float16* sbf = vt + BSD;                      // [B][S][S] f16 scores
  _Float16* abf = sbf + (long)B * SS;            // [B][S][S] f16 attn
  _Float16* hbf = qh;                            // PV out reuses qh

  _Float16* xph = (_Float16*)attnp;              // xp f16 in attn region of d_out

  dim3 blk(256);
  prep_w_kernel<<<dim3(16, 16), blk, 0, stream>>>(Wq, Wk, Wv, Wo, wqkv, woh);
  prep_misc_kernel<<<dim3(20), blk, 0, stream>>>(bq, bk, bv, bcat, pwtab);
  prep_x_kernel<<<dim3((int)(BSD / 1024)), blk, 0, stream>>>(x, pos, xph);

  dim3 blk5(512);
  // fused QKV projection: [16384,1024] @ [3072,1024]^T
  gemm256_kernel<EPI_QKV><<<dim3(12, 64, 1), blk5, 0, stream>>>(
      xph, wqkv, bcat, nullptr, nullptr, qh, kh, vt, B * S, 3 * D, D, 0, 0, 0);

  // scores (f16, pw-scaled): per-batch [2048,1024] @ [2048,1024]^T
  gemm256_kernel<EPI_SF16><<<dim3(8, 8, B), blk5, 0, stream>>>(
      qh, kh, nullptr, pwtab, nullptr, sbf, nullptr, nullptr, S, S, D, SD, SD, SS);

  softmax_kernel<<<dim3(B * S), blk, 0, stream>>>(sbf, attnp, abf);

  // PV: per-batch [2048,2048] @ [1024,2048]^T
  gemm256_kernel<EPI_PVO><<<dim3(4, 8, B), blk5, 0, stream>>>(
      abf, vt, nullptr, nullptr, nullptr, hbf, nullptr, nullptr, S, D, S, SS, SD, SD);

  // out-proj: [16384,1024] @ [1024,1024]^T + bo -> f32
  gemm256_kernel<EPI_F32B><<<dim3(4, 64, 1), blk5, 0, stream>>>(
      hbf, woh, bo, nullptr, outp, nullptr, nullptr, nullptr, B * S, D, D, 0, 0, 0);
}